// Round 8
// baseline (505.883 us; speedup 1.0000x reference)
//
#include <hip/hip_runtime.h>
#include <hip/hip_bf16.h>

// GAU fused pipeline for MI355X (gfx950), bf16-MFMA implementation.
// Shapes fixed: B=4, T=2048, D=1024, DF=2048, S=128.
//
// Structure: m97-style 128x128 MFMA GEMM (global_load_lds width-16 staging,
// 16x16x32 bf16 MFMA) with fused epilogues; materialized bf16 P (fits L3,
// recompute-free PV); two-pass masked softmax with per-wave key split.
//
// Defensive: if ws_size < required footprint, launch NOTHING (output stays
// poisoned -> clean validation failure instead of OOB writes killing the
// container). ws_size is constant across calls, so this is capture-safe.

typedef __attribute__((ext_vector_type(8))) short short8;
typedef __attribute__((ext_vector_type(4))) short short4v;
typedef __attribute__((ext_vector_type(4))) float f32x4;

#define NB 4
#define NT 2048
#define ND 1024
#define NDF 2048
#define NS 128
#define NM (NB * NT)

__device__ __forceinline__ float silu_f(float x) { return x / (1.f + __expf(-x)); }

__device__ __forceinline__ short bf16b(float x) {
  union { __hip_bfloat16 h; short s; } cv;
  cv.h = __float2bfloat16(x);
  return cv.s;
}

__device__ __forceinline__ void glds16(const void* g, void* l) {
  __builtin_amdgcn_global_load_lds(
      (const __attribute__((address_space(1))) unsigned int*)g,
      (__attribute__((address_space(3))) unsigned int*)l, 16, 0, 0);
}

// ---------------- fp32 -> bf16 elementwise convert (x) ----------------
__global__ void __launch_bounds__(256) cvt_bf16_k(const float* __restrict__ in,
                                                  __hip_bfloat16* __restrict__ out,
                                                  int n4) {
  int i = blockIdx.x * 256 + threadIdx.x;
  if (i >= n4) return;
  const float4 v = ((const float4*)in)[i];
  short4v pk;
  pk[0] = bf16b(v.x); pk[1] = bf16b(v.y); pk[2] = bf16b(v.z); pk[3] = bf16b(v.w);
  ((short4v*)out)[i] = pk;
}

// ---------------- (K x N) fp32 -> (N x K) bf16 transpose-convert ----------------
__global__ void __launch_bounds__(256) tr_cvt(const float* __restrict__ in,
                                              __hip_bfloat16* __restrict__ out,
                                              int K, int N) {
  __shared__ float tile[32][33];
  const int n0 = blockIdx.x * 32, k0 = blockIdx.y * 32;
  const int tx = threadIdx.x, ty = threadIdx.y;  // blockDim (32,8)
#pragma unroll
  for (int i = 0; i < 4; i++)
    tile[ty + i * 8][tx] = in[(long)(k0 + ty + i * 8) * N + n0 + tx];
  __syncthreads();
#pragma unroll
  for (int i = 0; i < 4; i++)
    out[(long)(n0 + ty + i * 8) * K + k0 + tx] = __float2bfloat16(tile[tx][ty + i * 8]);
}

// ---------------- templated 128x128 MFMA GEMM, epilogue variants ----------------
// A: (M x K) bf16 row-major (lda=K). Bt: (N x K) bf16 row-major (ldb=K).
enum { EU = 0, EV = 1, EQK = 2, EPV = 3, EOUT = 4 };

template <int EPI>
__global__ void __launch_bounds__(256) gemm_k(
    const __hip_bfloat16* __restrict__ A, const __hip_bfloat16* __restrict__ Bt,
    const int K, const long sA, const long sB,
    const float* __restrict__ bias, const float* __restrict__ gamma,
    const float* __restrict__ beta, const float* __restrict__ uqk,
    const __hip_bfloat16* __restrict__ uin,
    void* __restrict__ out0, void* __restrict__ out1) {
  __shared__ __hip_bfloat16 lA[128 * 32];
  __shared__ __hip_bfloat16 lB[128 * 32];
  const int tid = threadIdx.x;
  const int wave = tid >> 6, lane = tid & 63;
  const int l15 = lane & 15, lhi = lane >> 4;
  const int m0 = blockIdx.x * 128, n0 = blockIdx.y * 128;
  const long bz = blockIdx.z;
  const int wr = (wave >> 1) * 64, wc = (wave & 1) * 64;

  const __hip_bfloat16* Ab = A + bz * sA;
  const __hip_bfloat16* Bb = Bt + bz * sB;

  f32x4 acc[4][4] = {};

  // staging: tile = 128 rows x 32 bf16 = 8KB = 512 x 16B chunks; 256 threads, 2 rounds.
  const int c0 = tid, c1 = tid + 256;
  const __hip_bfloat16* gA0 = Ab + (long)(m0 + (c0 >> 2)) * K + (c0 & 3) * 8;
  const __hip_bfloat16* gA1 = Ab + (long)(m0 + (c1 >> 2)) * K + (c1 & 3) * 8;
  const __hip_bfloat16* gB0 = Bb + (long)(n0 + (c0 >> 2)) * K + (c0 & 3) * 8;
  const __hip_bfloat16* gB1 = Bb + (long)(n0 + (c1 >> 2)) * K + (c1 & 3) * 8;
  __hip_bfloat16* const lAp0 = &lA[wave * 512];         // wave-uniform LDS dests
  __hip_bfloat16* const lAp1 = &lA[2048 + wave * 512];
  __hip_bfloat16* const lBp0 = &lB[wave * 512];
  __hip_bfloat16* const lBp1 = &lB[2048 + wave * 512];

  for (int k0 = 0; k0 < K; k0 += 32) {
    glds16(gA0 + k0, lAp0);
    glds16(gA1 + k0, lAp1);
    glds16(gB0 + k0, lBp0);
    glds16(gB1 + k0, lBp1);
    __syncthreads();  // compiler drains vmcnt before s_barrier
    short8 af[4], bfv[4];
#pragma unroll
    for (int m = 0; m < 4; m++)
      af[m] = *(const short8*)&lA[(wr + m * 16 + l15) * 32 + lhi * 8];
#pragma unroll
    for (int n = 0; n < 4; n++)
      bfv[n] = *(const short8*)&lB[(wc + n * 16 + l15) * 32 + lhi * 8];
#pragma unroll
    for (int m = 0; m < 4; m++)
#pragma unroll
      for (int n = 0; n < 4; n++)
        acc[m][n] = __builtin_amdgcn_mfma_f32_16x16x32_bf16(af[m], bfv[n], acc[m][n], 0, 0, 0);
    __syncthreads();  // protect LDS before next stage
  }

  // epilogue: C/D layout col=lane&15, row=(lane>>4)*4+reg  [verified m89/m91]
#pragma unroll
  for (int m = 0; m < 4; m++) {
#pragma unroll
    for (int n = 0; n < 4; n++) {
      const int row0 = wr + m * 16 + lhi * 4;
      const int col = wc + n * 16 + l15;
      const int gm = m0 + row0;
      const int gn = n0 + col;
      if constexpr (EPI == EU) {
        const float bb = bias[gn];
        short* o = (short*)out0;
#pragma unroll
        for (int r = 0; r < 4; r++)
          o[(long)(gm + r) * NDF + gn] = bf16b(silu_f(acc[m][n][r] + bb));
      } else if constexpr (EPI == EV) {
        // store v transposed: vT (B, DF, T); 4 regs = 4 consecutive t -> 8B store
        const float bb = bias[gn];
        short4v pk;
#pragma unroll
        for (int r = 0; r < 4; r++) pk[r] = bf16b(silu_f(acc[m][n][r] + bb));
        const long bt = gm >> 11;  // T = 2048
        const int t = gm & (NT - 1);
        *(short4v*)((short*)out0 + bt * (long)NDF * NT + (long)gn * NT + t) = pk;
      } else if constexpr (EPI == EQK) {
        const float bb = bias[gn];
        const float g0 = gamma[gn], g1 = gamma[NS + gn];
        const float b0 = beta[gn], b1 = beta[NS + gn];
        const float uq = uqk[gn];
        short* oq = (short*)out0;
        short* ok = (short*)out1;
#pragma unroll
        for (int r = 0; r < 4; r++) {
          const float z = silu_f(acc[m][n][r] + bb);
          // q_scaled + u_qk folded: (z*g0+b0)/sqrt(S) + u_qk
          oq[(long)(gm + r) * NS + gn] = bf16b((z * g0 + b0) * 0.08838834764831845f + uq);
          ok[(long)(gm + r) * NS + gn] = bf16b(z * g1 + b1);
        }
      } else if constexpr (EPI == EPV) {
        const long base = bz * (long)NT * NDF;
        short* o = (short*)out0;
#pragma unroll
        for (int r = 0; r < 4; r++) {
          const long idx = base + (long)(gm + r) * NDF + gn;
          o[idx] = bf16b(acc[m][n][r] * __bfloat162float(uin[idx]));
        }
      } else {  // EOUT
        const float bb = bias[gn];
        float* o = (float*)out0;
#pragma unroll
        for (int r = 0; r < 4; r++)
          o[(long)(gm + r) * ND + gn] = acc[m][n][r] + bb;
      }
    }
  }
}

// ---------------- attention probabilities: P = softmax(mask(qu @ k^T)) ----------------
// block: 32 q-rows, 4 waves split the 2048 keys (512 each); two-pass (stats, then write).
__global__ void __launch_bounds__(256) attn_probs(const __hip_bfloat16* __restrict__ qu,
                                                  const __hip_bfloat16* __restrict__ kb,
                                                  const int* __restrict__ length,
                                                  __hip_bfloat16* __restrict__ P) {
  __shared__ __hip_bfloat16 lq[32 * 128];
  __shared__ float smax[4][32];
  __shared__ float ssum[4][32];
  const int tid = threadIdx.x, wave = tid >> 6, lane = tid & 63;
  const int l15 = lane & 15, lhi = lane >> 4;
  const int b = blockIdx.y, q0 = blockIdx.x * 32;
  const int len = length[b];
  const __hip_bfloat16* krow = kb + (long)b * NT * NS;

  for (int c = tid; c < 512; c += 256)  // 32x128 bf16 tile, 8-elem chunks
    *(short8*)&lq[c * 8] =
        *(const short8*)&qu[((long)b * NT + q0 + (c >> 4)) * NS + (c & 15) * 8];
  __syncthreads();

  short8 af[2][4];
#pragma unroll
  for (int m = 0; m < 2; m++)
#pragma unroll
    for (int s = 0; s < 4; s++)
      af[m][s] = *(const short8*)&lq[(m * 16 + l15) * NS + s * 32 + lhi * 8];

  float runm[8], runs[8];
#pragma unroll
  for (int i = 0; i < 8; i++) { runm[i] = -1e30f; runs[i] = 0.f; }

  const int kbase = wave * 512;
  // ---- pass 1: per-wave online max/sum ----
  for (int kt = 0; kt < 512; kt += 16) {
    const int key = kbase + kt + l15;
    short8 bfr[4];
#pragma unroll
    for (int s = 0; s < 4; s++)
      bfr[s] = *(const short8*)&krow[(long)key * NS + s * 32 + lhi * 8];
    f32x4 acc[2] = {};
#pragma unroll
    for (int m = 0; m < 2; m++)
#pragma unroll
      for (int s = 0; s < 4; s++)
        acc[m] = __builtin_amdgcn_mfma_f32_16x16x32_bf16(af[m][s], bfr[s], acc[m], 0, 0, 0);
    const bool valid = key < len;
#pragma unroll
    for (int m = 0; m < 2; m++)
#pragma unroll
      for (int r = 0; r < 4; r++) {
        float sc = valid ? acc[m][r] : -1e30f;
        float mx = sc;
        mx = fmaxf(mx, __shfl_xor(mx, 1));
        mx = fmaxf(mx, __shfl_xor(mx, 2));
        mx = fmaxf(mx, __shfl_xor(mx, 4));
        mx = fmaxf(mx, __shfl_xor(mx, 8));
        const int i = m * 4 + r;
        const float nm = fmaxf(runm[i], mx);
        float p = __expf(sc - nm);
        float ts = p;
        ts += __shfl_xor(ts, 1);
        ts += __shfl_xor(ts, 2);
        ts += __shfl_xor(ts, 4);
        ts += __shfl_xor(ts, 8);
        runs[i] = runs[i] * __expf(runm[i] - nm) + ts;
        runm[i] = nm;
      }
  }
  // publish per-wave stats (rows held redundantly across l15; lane l15==0 writes)
  if (l15 == 0) {
#pragma unroll
    for (int m = 0; m < 2; m++)
#pragma unroll
      for (int r = 0; r < 4; r++) {
        smax[wave][m * 16 + lhi * 4 + r] = runm[m * 4 + r];
        ssum[wave][m * 16 + lhi * 4 + r] = runs[m * 4 + r];
      }
  }
  __syncthreads();
  float fm[8], fi[8];
#pragma unroll
  for (int m = 0; m < 2; m++)
#pragma unroll
    for (int r = 0; r < 4; r++) {
      const int row = m * 16 + lhi * 4 + r;
      const float M4 = fmaxf(fmaxf(smax[0][row], smax[1][row]), fmaxf(smax[2][row], smax[3][row]));
      const float Ss = ssum[0][row] * __expf(smax[0][row] - M4) +
                       ssum[1][row] * __expf(smax[1][row] - M4) +
                       ssum[2][row] * __expf(smax[2][row] - M4) +
                       ssum[3][row] * __expf(smax[3][row] - M4);
      fm[m * 4 + r] = M4;
      fi[m * 4 + r] = 1.f / Ss;
    }
  // ---- pass 2: recompute scores, write normalized probs (bf16) ----
  short* Pb = (short*)P + (long)b * NT * NT;
  for (int kt = 0; kt < 512; kt += 16) {
    const int key = kbase + kt + l15;
    short8 bfr[4];
#pragma unroll
    for (int s = 0; s < 4; s++)
      bfr[s] = *(const short8*)&krow[(long)key * NS + s * 32 + lhi * 8];
    f32x4 acc[2] = {};
#pragma unroll
    for (int m = 0; m < 2; m++)
#pragma unroll
      for (int s = 0; s < 4; s++)
        acc[m] = __builtin_amdgcn_mfma_f32_16x16x32_bf16(af[m][s], bfr[s], acc[m], 0, 0, 0);
    const bool valid = key < len;
#pragma unroll
    for (int m = 0; m < 2; m++)
#pragma unroll
      for (int r = 0; r < 4; r++) {
        const float sc = valid ? acc[m][r] : -1e30f;
        const float p = __expf(sc - fm[m * 4 + r]) * fi[m * 4 + r];
        Pb[(long)(q0 + m * 16 + lhi * 4 + r) * NT + key] = bf16b(p);
      }
  }
}

// ---------------- host launch ----------------
extern "C" void kernel_launch(void* const* d_in, const int* in_sizes, int n_in,
                              void* d_out, int out_size, void* d_ws, size_t ws_size,
                              hipStream_t stream) {
  const float* x = (const float*)d_in[0];
  const int* length = (const int*)d_in[1];
  const float* Wu_w = (const float*)d_in[2];
  const float* Wu_b = (const float*)d_in[3];
  const float* Wv_w = (const float*)d_in[4];
  const float* Wv_b = (const float*)d_in[5];
  const float* Wqk_w = (const float*)d_in[6];
  const float* Wqk_b = (const float*)d_in[7];
  const float* Wo_w = (const float*)d_in[8];
  const float* Wo_b = (const float*)d_in[9];
  const float* gamma = (const float*)d_in[10];
  const float* beta = (const float*)d_in[11];
  const float* u_qk = (const float*)d_in[12];

  size_t off = 0;
  char* base = (char*)d_ws;
  auto alloc = [&](size_t bytes) -> char* {
    char* p = base + off;
    off += (bytes + 255) & ~(size_t)255;
    return p;
  };
  // -------- lifetime-aware workspace layout (peak ~134 MB) --------
  // persistent-to-end / long-lived buffers first:
  __hip_bfloat16* WoT = (__hip_bfloat16*)alloc((size_t)ND * NDF * 2);        // 4 MB, live to EOUT
  __hip_bfloat16* uB = (__hip_bfloat16*)alloc((size_t)NM * NDF * 2);         // 32 MB, EU -> EPV
  __hip_bfloat16* vT = (__hip_bfloat16*)alloc((size_t)NB * NDF * NT * 2);    // 32 MB, EV -> EPV
  __hip_bfloat16* Pbuf = (__hip_bfloat16*)alloc((size_t)NB * NT * NT * 2);   // 33.6 MB, attn -> EPV
  // scratch region R (32 MB): xb/WuT/WvT/WqkT/quB/kbB all dead before EPV;
  // outf (written by EPV) aliases R. (Pbuf cannot alias R: outf is written
  // by EPV while Pbuf is still being read by EPV.)
  char* R = alloc((size_t)NM * NDF * 2);                                     // 32 MB
  size_t roff = 0;
  auto ralloc = [&](size_t bytes) -> char* {
    char* p = R + roff;
    roff += (bytes + 255) & ~(size_t)255;
    return p;
  };
  __hip_bfloat16* xb = (__hip_bfloat16*)ralloc((size_t)NM * ND * 2);    // 16 MB, dead after EV
  __hip_bfloat16* WuT = (__hip_bfloat16*)ralloc((size_t)NDF * ND * 2);  // 4 MB, dead after EU
  __hip_bfloat16* WvT = (__hip_bfloat16*)ralloc((size_t)NDF * ND * 2);  // 4 MB, dead after EV
  __hip_bfloat16* WqkT = (__hip_bfloat16*)ralloc((size_t)NS * ND * 2);  // 0.25 MB, dead after EQK
  __hip_bfloat16* quB = (__hip_bfloat16*)ralloc((size_t)NM * NS * 2);   // 2 MB, dead after attn
  __hip_bfloat16* kbB = (__hip_bfloat16*)ralloc((size_t)NM * NS * 2);   // 2 MB, dead after attn
  __hip_bfloat16* outf = (__hip_bfloat16*)R;                            // aliases R (EPV -> EOUT)

  // Guard: if the workspace is smaller than our footprint, do NOT write OOB
  // (that can wedge the GPU/container). Launch nothing; the harness will
  // report a clean validation failure we can diagnose. ws_size is constant,
  // so behavior is identical on every call (capture-safe).
  if (ws_size < off) return;

  // converts / transposes
  cvt_bf16_k<<<dim3(NM * ND / 4 / 256), dim3(256), 0, stream>>>(x, xb, NM * ND / 4);
  tr_cvt<<<dim3(NDF / 32, ND / 32), dim3(32, 8), 0, stream>>>(Wu_w, WuT, ND, NDF);
  tr_cvt<<<dim3(NDF / 32, ND / 32), dim3(32, 8), 0, stream>>>(Wv_w, WvT, ND, NDF);
  tr_cvt<<<dim3(NS / 32, ND / 32), dim3(32, 8), 0, stream>>>(Wqk_w, WqkT, ND, NS);
  tr_cvt<<<dim3(ND / 32, NDF / 32), dim3(32, 8), 0, stream>>>(Wo_w, WoT, NDF, ND);

  // z -> qu, k
  gemm_k<EQK><<<dim3(NM / 128, 1, 1), dim3(256), 0, stream>>>(
      xb, WqkT, ND, 0, 0, Wqk_b, gamma, beta, u_qk, nullptr, quB, kbB);
  // u = silu(x@Wu+b)
  gemm_k<EU><<<dim3(NM / 128, NDF / 128, 1), dim3(256), 0, stream>>>(
      xb, WuT, ND, 0, 0, Wu_b, nullptr, nullptr, nullptr, nullptr, uB, nullptr);
  // vT = silu(x@Wv+b) transposed
  gemm_k<EV><<<dim3(NM / 128, NDF / 128, 1), dim3(256), 0, stream>>>(
      xb, WvT, ND, 0, 0, Wv_b, nullptr, nullptr, nullptr, nullptr, vT, nullptr);
  // P = softmax(mask(qu@k^T))
  attn_probs<<<dim3(NT / 32, NB), dim3(256), 0, stream>>>(quB, kbB, length, Pbuf);
  // out_f = u * (P @ v)   (batched)
  gemm_k<EPV><<<dim3(NT / 128, NDF / 128, NB), dim3(256), 0, stream>>>(
      Pbuf, vT, NT, (long)NT * NT, (long)NDF * NT, nullptr, nullptr, nullptr, nullptr,
      uB, outf, nullptr);
  // final = out_f @ Wo + b  (fp32 out)
  gemm_k<EOUT><<<dim3(NM / 128, ND / 128, 1), dim3(256), 0, stream>>>(
      outf, WoT, NDF, 0, 0, Wo_b, nullptr, nullptr, nullptr, nullptr, d_out, nullptr);

  (void)in_sizes; (void)n_in; (void)out_size;
}

// Round 11
// 457.186 us; speedup vs baseline: 1.1065x; 1.1065x over previous
//
#include <hip/hip_runtime.h>
#include <hip/hip_bf16.h>

// GAU fused pipeline for MI355X (gfx950), bf16-MFMA implementation.
// Shapes fixed: B=4, T=2048, D=1024, DF=2048, S=128.
//
// R8 change (pending A/B vs 506us baseline): gemm_k processes TWO 32-K
// sub-tiles per barrier window (BK=64 window, 2x LDS buffers, 8
// global_load_lds in flight, 32 MFMA/window) to halve the vmcnt(0)+barrier
// drain count — the stall identified by R8 counters (MfmaUtil 22%,
// VALUBusy 33%, HBM 20%: stall-bound, neither pipe saturated).

typedef __attribute__((ext_vector_type(8))) short short8;
typedef __attribute__((ext_vector_type(4))) short short4v;
typedef __attribute__((ext_vector_type(4))) float f32x4;

#define NB 4
#define NT 2048
#define ND 1024
#define NDF 2048
#define NS 128
#define NM (NB * NT)

__device__ __forceinline__ float silu_f(float x) { return x / (1.f + __expf(-x)); }

__device__ __forceinline__ short bf16b(float x) {
  union { __hip_bfloat16 h; short s; } cv;
  cv.h = __float2bfloat16(x);
  return cv.s;
}

__device__ __forceinline__ void glds16(const void* g, void* l) {
  __builtin_amdgcn_global_load_lds(
      (const __attribute__((address_space(1))) unsigned int*)g,
      (__attribute__((address_space(3))) unsigned int*)l, 16, 0, 0);
}

// ---------------- fp32 -> bf16 elementwise convert (x) ----------------
__global__ void __launch_bounds__(256) cvt_bf16_k(const float* __restrict__ in,
                                                  __hip_bfloat16* __restrict__ out,
                                                  int n4) {
  int i = blockIdx.x * 256 + threadIdx.x;
  if (i >= n4) return;
  const float4 v = ((const float4*)in)[i];
  short4v pk;
  pk[0] = bf16b(v.x); pk[1] = bf16b(v.y); pk[2] = bf16b(v.z); pk[3] = bf16b(v.w);
  ((short4v*)out)[i] = pk;
}

// ---------------- (K x N) fp32 -> (N x K) bf16 transpose-convert ----------------
__global__ void __launch_bounds__(256) tr_cvt(const float* __restrict__ in,
                                              __hip_bfloat16* __restrict__ out,
                                              int K, int N) {
  __shared__ float tile[32][33];
  const int n0 = blockIdx.x * 32, k0 = blockIdx.y * 32;
  const int tx = threadIdx.x, ty = threadIdx.y;  // blockDim (32,8)
#pragma unroll
  for (int i = 0; i < 4; i++)
    tile[ty + i * 8][tx] = in[(long)(k0 + ty + i * 8) * N + n0 + tx];
  __syncthreads();
#pragma unroll
  for (int i = 0; i < 4; i++)
    out[(long)(n0 + ty + i * 8) * K + k0 + tx] = __float2bfloat16(tile[tx][ty + i * 8]);
}

// ---------------- templated 128x128 MFMA GEMM, epilogue variants ----------------
// A: (M x K) bf16 row-major (lda=K). Bt: (N x K) bf16 row-major (ldb=K).
// K must be a multiple of 64 (all pipeline K's are: 1024 / 2048).
enum { EU = 0, EV = 1, EQK = 2, EPV = 3, EOUT = 4 };

template <int EPI>
__global__ void __launch_bounds__(256) gemm_k(
    const __hip_bfloat16* __restrict__ A, const __hip_bfloat16* __restrict__ Bt,
    const int K, const long sA, const long sB,
    const float* __restrict__ bias, const float* __restrict__ gamma,
    const float* __restrict__ beta, const float* __restrict__ uqk,
    const __hip_bfloat16* __restrict__ uin,
    void* __restrict__ out0, void* __restrict__ out1) {
  __shared__ __hip_bfloat16 lA[2][128 * 32];  // 2 x 8KB
  __shared__ __hip_bfloat16 lB[2][128 * 32];  // 2 x 8KB  (32KB total)
  const int tid = threadIdx.x;
  const int wave = tid >> 6, lane = tid & 63;
  const int l15 = lane & 15, lhi = lane >> 4;
  const int m0 = blockIdx.x * 128, n0 = blockIdx.y * 128;
  const long bz = blockIdx.z;
  const int wr = (wave >> 1) * 64, wc = (wave & 1) * 64;

  const __hip_bfloat16* Ab = A + bz * sA;
  const __hip_bfloat16* Bb = Bt + bz * sB;

  f32x4 acc[4][4] = {};

  // staging: each 128x32 sub-tile = 8KB = 512 x 16B chunks; 256 threads, 2 rounds.
  const int c0 = tid, c1 = tid + 256;
  const __hip_bfloat16* gA0 = Ab + (long)(m0 + (c0 >> 2)) * K + (c0 & 3) * 8;
  const __hip_bfloat16* gA1 = Ab + (long)(m0 + (c1 >> 2)) * K + (c1 & 3) * 8;
  const __hip_bfloat16* gB0 = Bb + (long)(n0 + (c0 >> 2)) * K + (c0 & 3) * 8;
  const __hip_bfloat16* gB1 = Bb + (long)(n0 + (c1 >> 2)) * K + (c1 & 3) * 8;
  // wave-uniform LDS dests (glds16 writes base + lane*16B)
  __hip_bfloat16* const lAp0 = &lA[0][wave * 512];
  __hip_bfloat16* const lAp1 = &lA[0][2048 + wave * 512];
  __hip_bfloat16* const lBp0 = &lB[0][wave * 512];
  __hip_bfloat16* const lBp1 = &lB[0][2048 + wave * 512];
  __hip_bfloat16* const lAq0 = &lA[1][wave * 512];
  __hip_bfloat16* const lAq1 = &lA[1][2048 + wave * 512];
  __hip_bfloat16* const lBq0 = &lB[1][wave * 512];
  __hip_bfloat16* const lBq1 = &lB[1][2048 + wave * 512];

  for (int k0 = 0; k0 < K; k0 += 64) {
    // issue both sub-tiles' loads (8 in flight), then one drain+barrier
    glds16(gA0 + k0, lAp0);
    glds16(gA1 + k0, lAp1);
    glds16(gB0 + k0, lBp0);
    glds16(gB1 + k0, lBp1);
    glds16(gA0 + k0 + 32, lAq0);
    glds16(gA1 + k0 + 32, lAq1);
    glds16(gB0 + k0 + 32, lBq0);
    glds16(gB1 + k0 + 32, lBq1);
    __syncthreads();  // compiler drains vmcnt before s_barrier
#pragma unroll
    for (int s = 0; s < 2; s++) {
      short8 af[4], bfv[4];
#pragma unroll
      for (int m = 0; m < 4; m++)
        af[m] = *(const short8*)&lA[s][(wr + m * 16 + l15) * 32 + lhi * 8];
#pragma unroll
      for (int n = 0; n < 4; n++)
        bfv[n] = *(const short8*)&lB[s][(wc + n * 16 + l15) * 32 + lhi * 8];
#pragma unroll
      for (int m = 0; m < 4; m++)
#pragma unroll
        for (int n = 0; n < 4; n++)
          acc[m][n] = __builtin_amdgcn_mfma_f32_16x16x32_bf16(af[m], bfv[n], acc[m][n], 0, 0, 0);
    }
    __syncthreads();  // protect LDS before next stage
  }

  // epilogue: C/D layout col=lane&15, row=(lane>>4)*4+reg  [verified m89/m91]
#pragma unroll
  for (int m = 0; m < 4; m++) {
#pragma unroll
    for (int n = 0; n < 4; n++) {
      const int row0 = wr + m * 16 + lhi * 4;
      const int col = wc + n * 16 + l15;
      const int gm = m0 + row0;
      const int gn = n0 + col;
      if constexpr (EPI == EU) {
        const float bb = bias[gn];
        short* o = (short*)out0;
#pragma unroll
        for (int r = 0; r < 4; r++)
          o[(long)(gm + r) * NDF + gn] = bf16b(silu_f(acc[m][n][r] + bb));
      } else if constexpr (EPI == EV) {
        // store v transposed: vT (B, DF, T); 4 regs = 4 consecutive t -> 8B store
        const float bb = bias[gn];
        short4v pk;
#pragma unroll
        for (int r = 0; r < 4; r++) pk[r] = bf16b(silu_f(acc[m][n][r] + bb));
        const long bt = gm >> 11;  // T = 2048
        const int t = gm & (NT - 1);
        *(short4v*)((short*)out0 + bt * (long)NDF * NT + (long)gn * NT + t) = pk;
      } else if constexpr (EPI == EQK) {
        const float bb = bias[gn];
        const float g0 = gamma[gn], g1 = gamma[NS + gn];
        const float b0 = beta[gn], b1 = beta[NS + gn];
        const float uq = uqk[gn];
        short* oq = (short*)out0;
        short* ok = (short*)out1;
#pragma unroll
        for (int r = 0; r < 4; r++) {
          const float z = silu_f(acc[m][n][r] + bb);
          // q_scaled + u_qk folded: (z*g0+b0)/sqrt(S) + u_qk
          oq[(long)(gm + r) * NS + gn] = bf16b((z * g0 + b0) * 0.08838834764831845f + uq);
          ok[(long)(gm + r) * NS + gn] = bf16b(z * g1 + b1);
        }
      } else if constexpr (EPI == EPV) {
        const long base = bz * (long)NT * NDF;
        short* o = (short*)out0;
#pragma unroll
        for (int r = 0; r < 4; r++) {
          const long idx = base + (long)(gm + r) * NDF + gn;
          o[idx] = bf16b(acc[m][n][r] * __bfloat162float(uin[idx]));
        }
      } else {  // EOUT
        const float bb = bias[gn];
        float* o = (float*)out0;
#pragma unroll
        for (int r = 0; r < 4; r++)
          o[(long)(gm + r) * ND + gn] = acc[m][n][r] + bb;
      }
    }
  }
}

// ---------------- attention probabilities: P = softmax(mask(qu @ k^T)) ----------------
// block: 32 q-rows, 4 waves split the 2048 keys (512 each); two-pass (stats, then write).
__global__ void __launch_bounds__(256) attn_probs(const __hip_bfloat16* __restrict__ qu,
                                                  const __hip_bfloat16* __restrict__ kb,
                                                  const int* __restrict__ length,
                                                  __hip_bfloat16* __restrict__ P) {
  __shared__ __hip_bfloat16 lq[32 * 128];
  __shared__ float smax[4][32];
  __shared__ float ssum[4][32];
  const int tid = threadIdx.x, wave = tid >> 6, lane = tid & 63;
  const int l15 = lane & 15, lhi = lane >> 4;
  const int b = blockIdx.y, q0 = blockIdx.x * 32;
  const int len = length[b];
  const __hip_bfloat16* krow = kb + (long)b * NT * NS;

  for (int c = tid; c < 512; c += 256)  // 32x128 bf16 tile, 8-elem chunks
    *(short8*)&lq[c * 8] =
        *(const short8*)&qu[((long)b * NT + q0 + (c >> 4)) * NS + (c & 15) * 8];
  __syncthreads();

  short8 af[2][4];
#pragma unroll
  for (int m = 0; m < 2; m++)
#pragma unroll
    for (int s = 0; s < 4; s++)
      af[m][s] = *(const short8*)&lq[(m * 16 + l15) * NS + s * 32 + lhi * 8];

  float runm[8], runs[8];
#pragma unroll
  for (int i = 0; i < 8; i++) { runm[i] = -1e30f; runs[i] = 0.f; }

  const int kbase = wave * 512;
  // ---- pass 1: per-wave online max/sum ----
  for (int kt = 0; kt < 512; kt += 16) {
    const int key = kbase + kt + l15;
    short8 bfr[4];
#pragma unroll
    for (int s = 0; s < 4; s++)
      bfr[s] = *(const short8*)&krow[(long)key * NS + s * 32 + lhi * 8];
    f32x4 acc[2] = {};
#pragma unroll
    for (int m = 0; m < 2; m++)
#pragma unroll
      for (int s = 0; s < 4; s++)
        acc[m] = __builtin_amdgcn_mfma_f32_16x16x32_bf16(af[m][s], bfr[s], acc[m], 0, 0, 0);
    const bool valid = key < len;
#pragma unroll
    for (int m = 0; m < 2; m++)
#pragma unroll
      for (int r = 0; r < 4; r++) {
        float sc = valid ? acc[m][r] : -1e30f;
        float mx = sc;
        mx = fmaxf(mx, __shfl_xor(mx, 1));
        mx = fmaxf(mx, __shfl_xor(mx, 2));
        mx = fmaxf(mx, __shfl_xor(mx, 4));
        mx = fmaxf(mx, __shfl_xor(mx, 8));
        const int i = m * 4 + r;
        const float nm = fmaxf(runm[i], mx);
        float p = __expf(sc - nm);
        float ts = p;
        ts += __shfl_xor(ts, 1);
        ts += __shfl_xor(ts, 2);
        ts += __shfl_xor(ts, 4);
        ts += __shfl_xor(ts, 8);
        runs[i] = runs[i] * __expf(runm[i] - nm) + ts;
        runm[i] = nm;
      }
  }
  // publish per-wave stats (rows held redundantly across l15; lane l15==0 writes)
  if (l15 == 0) {
#pragma unroll
    for (int m = 0; m < 2; m++)
#pragma unroll
      for (int r = 0; r < 4; r++) {
        smax[wave][m * 16 + lhi * 4 + r] = runm[m * 4 + r];
        ssum[wave][m * 16 + lhi * 4 + r] = runs[m * 4 + r];
      }
  }
  __syncthreads();
  float fm[8], fi[8];
#pragma unroll
  for (int m = 0; m < 2; m++)
#pragma unroll
    for (int r = 0; r < 4; r++) {
      const int row = m * 16 + lhi * 4 + r;
      const float M4 = fmaxf(fmaxf(smax[0][row], smax[1][row]), fmaxf(smax[2][row], smax[3][row]));
      const float Ss = ssum[0][row] * __expf(smax[0][row] - M4) +
                       ssum[1][row] * __expf(smax[1][row] - M4) +
                       ssum[2][row] * __expf(smax[2][row] - M4) +
                       ssum[3][row] * __expf(smax[3][row] - M4);
      fm[m * 4 + r] = M4;
      fi[m * 4 + r] = 1.f / Ss;
    }
  // ---- pass 2: recompute scores, write normalized probs (bf16) ----
  short* Pb = (short*)P + (long)b * NT * NT;
  for (int kt = 0; kt < 512; kt += 16) {
    const int key = kbase + kt + l15;
    short8 bfr[4];
#pragma unroll
    for (int s = 0; s < 4; s++)
      bfr[s] = *(const short8*)&krow[(long)key * NS + s * 32 + lhi * 8];
    f32x4 acc[2] = {};
#pragma unroll
    for (int m = 0; m < 2; m++)
#pragma unroll
      for (int s = 0; s < 4; s++)
        acc[m] = __builtin_amdgcn_mfma_f32_16x16x32_bf16(af[m][s], bfr[s], acc[m], 0, 0, 0);
    const bool valid = key < len;
#pragma unroll
    for (int m = 0; m < 2; m++)
#pragma unroll
      for (int r = 0; r < 4; r++) {
        const float sc = valid ? acc[m][r] : -1e30f;
        const float p = __expf(sc - fm[m * 4 + r]) * fi[m * 4 + r];
        Pb[(long)(q0 + m * 16 + lhi * 4 + r) * NT + key] = bf16b(p);
      }
  }
}

// ---------------- host launch ----------------
extern "C" void kernel_launch(void* const* d_in, const int* in_sizes, int n_in,
                              void* d_out, int out_size, void* d_ws, size_t ws_size,
                              hipStream_t stream) {
  const float* x = (const float*)d_in[0];
  const int* length = (const int*)d_in[1];
  const float* Wu_w = (const float*)d_in[2];
  const float* Wu_b = (const float*)d_in[3];
  const float* Wv_w = (const float*)d_in[4];
  const float* Wv_b = (const float*)d_in[5];
  const float* Wqk_w = (const float*)d_in[6];
  const float* Wqk_b = (const float*)d_in[7];
  const float* Wo_w = (const float*)d_in[8];
  const float* Wo_b = (const float*)d_in[9];
  const float* gamma = (const float*)d_in[10];
  const float* beta = (const float*)d_in[11];
  const float* u_qk = (const float*)d_in[12];

  size_t off = 0;
  char* base = (char*)d_ws;
  auto alloc = [&](size_t bytes) -> char* {
    char* p = base + off;
    off += (bytes + 255) & ~(size_t)255;
    return p;
  };
  // -------- lifetime-aware workspace layout (peak ~134 MB) --------
  __hip_bfloat16* WoT = (__hip_bfloat16*)alloc((size_t)ND * NDF * 2);        // 4 MB, live to EOUT
  __hip_bfloat16* uB = (__hip_bfloat16*)alloc((size_t)NM * NDF * 2);         // 32 MB, EU -> EPV
  __hip_bfloat16* vT = (__hip_bfloat16*)alloc((size_t)NB * NDF * NT * 2);    // 32 MB, EV -> EPV
  __hip_bfloat16* Pbuf = (__hip_bfloat16*)alloc((size_t)NB * NT * NT * 2);   // 33.6 MB, attn -> EPV
  char* R = alloc((size_t)NM * NDF * 2);                                     // 32 MB scratch
  size_t roff = 0;
  auto ralloc = [&](size_t bytes) -> char* {
    char* p = R + roff;
    roff += (bytes + 255) & ~(size_t)255;
    return p;
  };
  __hip_bfloat16* xb = (__hip_bfloat16*)ralloc((size_t)NM * ND * 2);    // 16 MB, dead after EV
  __hip_bfloat16* WuT = (__hip_bfloat16*)ralloc((size_t)NDF * ND * 2);  // 4 MB, dead after EU
  __hip_bfloat16* WvT = (__hip_bfloat16*)ralloc((size_t)NDF * ND * 2);  // 4 MB, dead after EV
  __hip_bfloat16* WqkT = (__hip_bfloat16*)ralloc((size_t)NS * ND * 2);  // 0.25 MB, dead after EQK
  __hip_bfloat16* quB = (__hip_bfloat16*)ralloc((size_t)NM * NS * 2);   // 2 MB, dead after attn
  __hip_bfloat16* kbB = (__hip_bfloat16*)ralloc((size_t)NM * NS * 2);   // 2 MB, dead after attn
  __hip_bfloat16* outf = (__hip_bfloat16*)R;                            // aliases R (EPV -> EOUT)

  // Guard: if workspace smaller than footprint, launch nothing (clean fail).
  if (ws_size < off) return;

  // converts / transposes
  cvt_bf16_k<<<dim3(NM * ND / 4 / 256), dim3(256), 0, stream>>>(x, xb, NM * ND / 4);
  tr_cvt<<<dim3(NDF / 32, ND / 32), dim3(32, 8), 0, stream>>>(Wu_w, WuT, ND, NDF);
  tr_cvt<<<dim3(NDF / 32, ND / 32), dim3(32, 8), 0, stream>>>(Wv_w, WvT, ND, NDF);
  tr_cvt<<<dim3(NS / 32, ND / 32), dim3(32, 8), 0, stream>>>(Wqk_w, WqkT, ND, NS);
  tr_cvt<<<dim3(ND / 32, NDF / 32), dim3(32, 8), 0, stream>>>(Wo_w, WoT, NDF, ND);

  // z -> qu, k
  gemm_k<EQK><<<dim3(NM / 128, 1, 1), dim3(256), 0, stream>>>(
      xb, WqkT, ND, 0, 0, Wqk_b, gamma, beta, u_qk, nullptr, quB, kbB);
  // u = silu(x@Wu+b)
  gemm_k<EU><<<dim3(NM / 128, NDF / 128, 1), dim3(256), 0, stream>>>(
      xb, WuT, ND, 0, 0, Wu_b, nullptr, nullptr, nullptr, nullptr, uB, nullptr);
  // vT = silu(x@Wv+b) transposed
  gemm_k<EV><<<dim3(NM / 128, NDF / 128, 1), dim3(256), 0, stream>>>(
      xb, WvT, ND, 0, 0, Wv_b, nullptr, nullptr, nullptr, nullptr, vT, nullptr);
  // P = softmax(mask(qu@k^T))
  attn_probs<<<dim3(NT / 32, NB), dim3(256), 0, stream>>>(quB, kbB, length, Pbuf);
  // out_f = u * (P @ v)   (batched)
  gemm_k<EPV><<<dim3(NT / 128, NDF / 128, NB), dim3(256), 0, stream>>>(
      Pbuf, vT, NT, (long)NT * NT, (long)NDF * NT, nullptr, nullptr, nullptr, nullptr,
      uB, outf, nullptr);
  // final = out_f @ Wo + b  (fp32 out)
  gemm_k<EOUT><<<dim3(NM / 128, ND / 128, 1), dim3(256), 0, stream>>>(
      outf, WoT, NDF, 0, 0, Wo_b, nullptr, nullptr, nullptr, nullptr, d_out, nullptr);

  (void)in_sizes; (void)n_in; (void)out_size;
}